// Round 1
// baseline (103.260 us; speedup 1.0000x reference)
//
#include <hip/hip_runtime.h>
#include <math.h>

#define N_NODES 8192
#define WPR 256               // words per bitmask row = N/32
#define LR_C 0.01f
#define EPS_C 1e-6f

// ---------------- kernel 1: distance-constraint scatter ----------------
__global__ void scatter_constraints(const float* __restrict__ x0,
                                    const int* __restrict__ dist_idx,
                                    const float* __restrict__ dist_target,
                                    float* __restrict__ x1, int K) {
    int k = blockIdx.x * blockDim.x + threadIdx.x;
    if (k >= K) return;
    int i = dist_idx[2 * k], j = dist_idx[2 * k + 1];
    float ax = x0[3 * i], ay = x0[3 * i + 1], az = x0[3 * i + 2];
    float bx = x0[3 * j], by = x0[3 * j + 1], bz = x0[3 * j + 2];
    float vx = ax - bx, vy = ay - by, vz = az - bz;
    float dist = sqrtf(vx * vx + vy * vy + vz * vz + 1e-12f);
    bool valid = (dist > EPS_C) && (i != j);
    float coef = valid ? (LR_C * 0.5f) * (dist - dist_target[k]) / dist : 0.0f;
    if (coef != 0.0f) {
        float cx = coef * vx, cy = coef * vy, cz = coef * vz;
        atomicAdd(&x1[3 * i],     -cx);
        atomicAdd(&x1[3 * i + 1], -cy);
        atomicAdd(&x1[3 * i + 2], -cz);
        atomicAdd(&x1[3 * j],      cx);
        atomicAdd(&x1[3 * j + 1],  cy);
        atomicAdd(&x1[3 * j + 2],  cz);
    }
}

// ---------------- kernel 2: pairwise repulsion partials ----------------
// grid = (N/256 row-chunks, 32 j-chunks), block = 256
__global__ __launch_bounds__(256) void repulsion_partial(
        const float* __restrict__ x1, const float* __restrict__ min_dist,
        float4* __restrict__ partials) {
    __shared__ float4 pj[256];
    int t = threadIdx.x;
    int jbase = blockIdx.y * 256;
    int i = blockIdx.x * 256 + t;
    {
        int j = jbase + t;
        float a = x1[3 * j], b = x1[3 * j + 1], c = x1[3 * j + 2];
        pj[t] = make_float4(a, b, c, a * a + b * b + c * c);
    }
    __syncthreads();
    float xi = x1[3 * i], yi = x1[3 * i + 1], zi = x1[3 * i + 2];
    float sqi = xi * xi + yi * yi + zi * zi;
    float md = min_dist[0];
    float md2 = md * md;
    const float c0 = 0.5f * LR_C;          // 0.005
    float c1 = c0 * md;
    int di = i - jbase;                    // diagonal position in this tile (may be OOR)
    float S = 0.f, axc = 0.f, ayc = 0.f, azc = 0.f;
    #pragma unroll 4
    for (int jj = 0; jj < 256; ++jj) {
        float4 p = pj[jj];
        float dot = fmaf(xi, p.x, fmaf(yi, p.y, zi * p.z));
        float d2 = fmaxf(fmaf(-2.0f, dot, sqi + p.w), 1e-12f);
        float r = __builtin_amdgcn_rsqf(d2);
        bool m = (d2 < md2) && (d2 > 1e-12f) && (jj != di);
        float w = m ? fmaf(c1, r, -c0) : 0.0f;   // 0.005*(md/d - 1)
        S += w;
        axc = fmaf(w, p.x, axc);
        ayc = fmaf(w, p.y, ayc);
        azc = fmaf(w, p.z, azc);
    }
    partials[blockIdx.y * N_NODES + i] = make_float4(axc, ayc, azc, S);
}

// ---------------- kernel 3: reduce partials, finalize x2 ----------------
__global__ void repulsion_finalize(const float* __restrict__ x1,
                                   const float4* __restrict__ partials,
                                   float* __restrict__ x2,
                                   float* __restrict__ out_x, int nchunks) {
    int i = blockIdx.x * blockDim.x + threadIdx.x;
    if (i >= N_NODES) return;
    float S = 0.f, axc = 0.f, ayc = 0.f, azc = 0.f;
    for (int c = 0; c < nchunks; ++c) {
        float4 p = partials[c * N_NODES + i];
        axc += p.x; ayc += p.y; azc += p.z; S += p.w;
    }
    float xi = x1[3 * i], yi = x1[3 * i + 1], zi = x1[3 * i + 2];
    float ox = xi + xi * S - axc;
    float oy = yi + yi * S - ayc;
    float oz = zi + zi * S - azc;
    x2[3 * i] = ox; x2[3 * i + 1] = oy; x2[3 * i + 2] = oz;
    out_x[3 * i] = ox; out_x[3 * i + 1] = oy; out_x[3 * i + 2] = oz;
}

// ---------------- kernel 4: adjacency bitmasks (set semantics) ----------------
__global__ void build_adj(const int* __restrict__ edge_index,
                          unsigned int* __restrict__ A,
                          unsigned int* __restrict__ B, int E) {
    int k = blockIdx.x * blockDim.x + threadIdx.x;
    if (k >= E) return;
    int a = edge_index[k];
    int b = edge_index[E + k];
    a = min(max(a, 0), N_NODES - 1);
    b = min(max(b, 0), N_NODES - 1);
    atomicOr(&A[a * WPR + (b >> 5)], 1u << (b & 31));
    atomicOr(&B[b * WPR + (a >> 5)], 1u << (a & 31));
}

// ---------------- kernel 5: degree -> dinv, z = dinv * x2 ----------------
// one wave (64 lanes) per row; block = 256 -> 4 rows/block
__global__ __launch_bounds__(256) void degree_kernel(
        const unsigned int* __restrict__ A, const unsigned int* __restrict__ B,
        const float* __restrict__ x2, float* __restrict__ dinv,
        float4* __restrict__ z4) {
    int row = (blockIdx.x * blockDim.x + threadIdx.x) >> 6;
    int lane = threadIdx.x & 63;
    if (row >= N_NODES) return;
    const unsigned int* ra = A + (size_t)row * WPR;
    const unsigned int* rb = B + (size_t)row * WPR;
    int cnt = 0;
    #pragma unroll
    for (int q = 0; q < 4; ++q) {
        cnt += __popc(ra[q * 64 + lane]);
        cnt += __popc(rb[q * 64 + lane]);
    }
    for (int off = 32; off; off >>= 1) cnt += __shfl_down(cnt, off);
    if (lane == 0) {
        float dv = (cnt == 0) ? 0.0f : 1.0f / sqrtf((float)cnt + EPS_C);
        dinv[row] = dv;
        z4[row] = make_float4(dv * x2[3 * row], dv * x2[3 * row + 1],
                              dv * x2[3 * row + 2], dv);
    }
}

// ---------------- kernel 6: Laplacian gather + curvature ----------------
__global__ __launch_bounds__(256) void lap_kernel(
        const unsigned int* __restrict__ A, const unsigned int* __restrict__ B,
        const float* __restrict__ x2, const float* __restrict__ dinv,
        const float4* __restrict__ z4, float* __restrict__ out_curv) {
    int row = (blockIdx.x * blockDim.x + threadIdx.x) >> 6;
    int lane = threadIdx.x & 63;
    if (row >= N_NODES) return;
    float axc = 0.f, ayc = 0.f, azc = 0.f;
    #pragma unroll
    for (int q = 0; q < 4; ++q) {
        int wi = q * 64 + lane;
        unsigned int w = A[(size_t)row * WPR + wi];
        while (w) {
            int b = __ffs(w) - 1; w &= w - 1;
            float4 z = z4[wi * 32 + b];
            axc += z.x; ayc += z.y; azc += z.z;
        }
        w = B[(size_t)row * WPR + wi];
        while (w) {
            int b = __ffs(w) - 1; w &= w - 1;
            float4 z = z4[wi * 32 + b];
            axc += z.x; ayc += z.y; azc += z.z;
        }
    }
    for (int off = 32; off; off >>= 1) {
        axc += __shfl_down(axc, off);
        ayc += __shfl_down(ayc, off);
        azc += __shfl_down(azc, off);
    }
    if (lane == 0) {
        float dv = dinv[row];
        float lx = x2[3 * row]     - dv * axc;
        float ly = x2[3 * row + 1] - dv * ayc;
        float lz = x2[3 * row + 2] - dv * azc;
        out_curv[row] = sqrtf(lx * lx + ly * ly + lz * lz + 1e-12f);
    }
}

extern "C" void kernel_launch(void* const* d_in, const int* in_sizes, int n_in,
                              void* d_out, int out_size, void* d_ws, size_t ws_size,
                              hipStream_t stream) {
    const float* positions   = (const float*)d_in[0];
    const int*   edge_index  = (const int*)d_in[1];
    const int*   dist_idx    = (const int*)d_in[2];
    const float* dist_target = (const float*)d_in[3];
    const float* min_dist    = (const float*)d_in[4];
    float* out = (float*)d_out;

    const int E = in_sizes[1] / 2;   // 262144
    const int K = in_sizes[2] / 2;   // 65536
    const int NJ = 32;               // j-chunks in repulsion

    // workspace layout (16B aligned)
    char* ws = (char*)d_ws;
    const size_t X1_OFF   = 0;
    const size_t X2_OFF   = X1_OFF + (size_t)N_NODES * 3 * 4;          //  96 KiB
    const size_t Z4_OFF   = X2_OFF + (size_t)N_NODES * 3 * 4;          //  96 KiB
    const size_t DINV_OFF = Z4_OFF + (size_t)N_NODES * 16;             // 128 KiB
    const size_t PART_OFF = DINV_OFF + (size_t)N_NODES * 4;            //  32 KiB
    const size_t ADJ_OFF  = PART_OFF + (size_t)NJ * N_NODES * 16;      //   4 MiB
    const size_t ADJ_BYTES = (size_t)N_NODES * WPR * 4;                //   8 MiB each

    float* x1         = (float*)(ws + X1_OFF);
    float* x2         = (float*)(ws + X2_OFF);
    float4* z4        = (float4*)(ws + Z4_OFF);
    float* dinv       = (float*)(ws + DINV_OFF);
    float4* partials  = (float4*)(ws + PART_OFF);
    unsigned int* A   = (unsigned int*)(ws + ADJ_OFF);
    unsigned int* B   = (unsigned int*)(ws + ADJ_OFF + ADJ_BYTES);

    // x1 = positions (then scatter-add corrections); A,B bitmasks = 0
    hipMemcpyAsync(x1, positions, (size_t)N_NODES * 3 * 4,
                   hipMemcpyDeviceToDevice, stream);
    hipMemsetAsync(A, 0, 2 * ADJ_BYTES, stream);

    scatter_constraints<<<(K + 255) / 256, 256, 0, stream>>>(
        positions, dist_idx, dist_target, x1, K);

    dim3 grid_rep(N_NODES / 256, NJ);
    repulsion_partial<<<grid_rep, 256, 0, stream>>>(x1, min_dist, partials);

    repulsion_finalize<<<N_NODES / 256, 256, 0, stream>>>(
        x1, partials, x2, out, NJ);

    build_adj<<<(E + 255) / 256, 256, 0, stream>>>(edge_index, A, B, E);

    int rows_per_block = 256 / 64;
    int nblk = N_NODES / rows_per_block;   // 2048
    degree_kernel<<<nblk, 256, 0, stream>>>(A, B, x2, dinv, z4);
    lap_kernel<<<nblk, 256, 0, stream>>>(A, B, x2, dinv, z4, out + 3 * N_NODES);
}

// Round 2
// 97.855 us; speedup vs baseline: 1.0552x; 1.0552x over previous
//
#include <hip/hip_runtime.h>
#include <math.h>

#define N_NODES 8192
#define WPR 256               // words per bitmask row = N/32
#define LR_C 0.01f
#define EPS_C 1e-6f

// ---------------- kernel 0: clear adjacency bitmasks + init x1 ----------------
// grid = 4096 x 256: each thread stores one uint4 (16B) -> exactly 16 MiB.
// threads < 6144 also copy positions (8192*3 floats = 6144 float4) into x1.
__global__ __launch_bounds__(256) void init_clear(const float4* __restrict__ pos4,
                                                  float4* __restrict__ x1_4,
                                                  uint4* __restrict__ adj) {
    int gid = blockIdx.x * blockDim.x + threadIdx.x;
    adj[gid] = make_uint4(0u, 0u, 0u, 0u);
    if (gid < 6144) x1_4[gid] = pos4[gid];
}

// ---------------- kernel 1: distance-constraint scatter ----------------
__global__ void scatter_constraints(const float* __restrict__ x0,
                                    const int* __restrict__ dist_idx,
                                    const float* __restrict__ dist_target,
                                    float* __restrict__ x1, int K) {
    int k = blockIdx.x * blockDim.x + threadIdx.x;
    if (k >= K) return;
    int i = dist_idx[2 * k], j = dist_idx[2 * k + 1];
    float ax = x0[3 * i], ay = x0[3 * i + 1], az = x0[3 * i + 2];
    float bx = x0[3 * j], by = x0[3 * j + 1], bz = x0[3 * j + 2];
    float vx = ax - bx, vy = ay - by, vz = az - bz;
    float dist = sqrtf(vx * vx + vy * vy + vz * vz + 1e-12f);
    bool valid = (dist > EPS_C) && (i != j);
    float coef = valid ? (LR_C * 0.5f) * (dist - dist_target[k]) / dist : 0.0f;
    if (coef != 0.0f) {
        float cx = coef * vx, cy = coef * vy, cz = coef * vz;
        atomicAdd(&x1[3 * i],     -cx);
        atomicAdd(&x1[3 * i + 1], -cy);
        atomicAdd(&x1[3 * i + 2], -cz);
        atomicAdd(&x1[3 * j],      cx);
        atomicAdd(&x1[3 * j + 1],  cy);
        atomicAdd(&x1[3 * j + 2],  cz);
    }
}

// ---------------- kernel 2: adjacency bitmasks (set semantics) ----------------
__global__ void build_adj(const int* __restrict__ edge_index,
                          unsigned int* __restrict__ A,
                          unsigned int* __restrict__ B, int E) {
    int k = blockIdx.x * blockDim.x + threadIdx.x;
    if (k >= E) return;
    int a = edge_index[k];
    int b = edge_index[E + k];
    a = min(max(a, 0), N_NODES - 1);
    b = min(max(b, 0), N_NODES - 1);
    atomicOr(&A[a * WPR + (b >> 5)], 1u << (b & 31));
    atomicOr(&B[b * WPR + (a >> 5)], 1u << (a & 31));
}

// ---------------- kernel 3: pairwise repulsion partials ----------------
// grid = (N/256 row-chunks, 32 j-chunks), block = 256
__global__ __launch_bounds__(256) void repulsion_partial(
        const float* __restrict__ x1, const float* __restrict__ min_dist,
        float4* __restrict__ partials) {
    __shared__ float4 pj[256];
    int t = threadIdx.x;
    int jbase = blockIdx.y * 256;
    int i = blockIdx.x * 256 + t;
    {
        int j = jbase + t;
        float a = x1[3 * j], b = x1[3 * j + 1], c = x1[3 * j + 2];
        pj[t] = make_float4(a, b, c, a * a + b * b + c * c);
    }
    __syncthreads();
    float xi = x1[3 * i], yi = x1[3 * i + 1], zi = x1[3 * i + 2];
    float sqi = xi * xi + yi * yi + zi * zi;
    float md = min_dist[0];
    float md2 = md * md;
    const float c0 = 0.5f * LR_C;          // 0.005
    float c1 = c0 * md;
    int di = i - jbase;                    // diagonal position in this tile (may be OOR)
    float S = 0.f, axc = 0.f, ayc = 0.f, azc = 0.f;
    #pragma unroll 4
    for (int jj = 0; jj < 256; ++jj) {
        float4 p = pj[jj];
        float dot = fmaf(xi, p.x, fmaf(yi, p.y, zi * p.z));
        float d2 = fmaxf(fmaf(-2.0f, dot, sqi + p.w), 1e-12f);
        float r = __builtin_amdgcn_rsqf(d2);
        bool m = (d2 < md2) && (d2 > 1e-12f) && (jj != di);
        float w = m ? fmaf(c1, r, -c0) : 0.0f;   // 0.005*(md/d - 1)
        S += w;
        axc = fmaf(w, p.x, axc);
        ayc = fmaf(w, p.y, ayc);
        azc = fmaf(w, p.z, azc);
    }
    partials[blockIdx.y * N_NODES + i] = make_float4(axc, ayc, azc, S);
}

// ---------------- kernel 4: fused finalize + degree ----------------
// one wave (64 lanes) per row; block = 256 -> 4 rows/block
__global__ __launch_bounds__(256) void finalize_degree(
        const float* __restrict__ x1,
        const float4* __restrict__ partials,
        const unsigned int* __restrict__ A, const unsigned int* __restrict__ B,
        float* __restrict__ x2, float* __restrict__ out_x,
        float* __restrict__ dinv, float4* __restrict__ z4) {
    int row = (blockIdx.x * blockDim.x + threadIdx.x) >> 6;
    int lane = threadIdx.x & 63;
    if (row >= N_NODES) return;
    int cnt = 0;
    #pragma unroll
    for (int q = 0; q < 4; ++q) {
        cnt += __popc(A[(size_t)row * WPR + q * 64 + lane]);
        cnt += __popc(B[(size_t)row * WPR + q * 64 + lane]);
    }
    float axc = 0.f, ayc = 0.f, azc = 0.f, S = 0.f;
    if (lane < 32) {
        float4 p = partials[lane * N_NODES + row];
        axc = p.x; ayc = p.y; azc = p.z; S = p.w;
    }
    for (int off = 32; off; off >>= 1) {
        axc += __shfl_down(axc, off);
        ayc += __shfl_down(ayc, off);
        azc += __shfl_down(azc, off);
        S   += __shfl_down(S, off);
        cnt += __shfl_down(cnt, off);
    }
    if (lane == 0) {
        float xi = x1[3 * row], yi = x1[3 * row + 1], zi = x1[3 * row + 2];
        float ox = xi + xi * S - axc;
        float oy = yi + yi * S - ayc;
        float oz = zi + zi * S - azc;
        x2[3 * row] = ox; x2[3 * row + 1] = oy; x2[3 * row + 2] = oz;
        out_x[3 * row] = ox; out_x[3 * row + 1] = oy; out_x[3 * row + 2] = oz;
        float dv = (cnt == 0) ? 0.0f : 1.0f / sqrtf((float)cnt + EPS_C);
        dinv[row] = dv;
        z4[row] = make_float4(dv * ox, dv * oy, dv * oz, dv);
    }
}

// ---------------- kernel 5: Laplacian gather + curvature ----------------
__global__ __launch_bounds__(256) void lap_kernel(
        const unsigned int* __restrict__ A, const unsigned int* __restrict__ B,
        const float* __restrict__ x2, const float* __restrict__ dinv,
        const float4* __restrict__ z4, float* __restrict__ out_curv) {
    int row = (blockIdx.x * blockDim.x + threadIdx.x) >> 6;
    int lane = threadIdx.x & 63;
    if (row >= N_NODES) return;
    float axc = 0.f, ayc = 0.f, azc = 0.f;
    #pragma unroll
    for (int q = 0; q < 4; ++q) {
        int wi = q * 64 + lane;
        unsigned int w = A[(size_t)row * WPR + wi];
        while (w) {
            int b = __ffs(w) - 1; w &= w - 1;
            float4 z = z4[wi * 32 + b];
            axc += z.x; ayc += z.y; azc += z.z;
        }
        w = B[(size_t)row * WPR + wi];
        while (w) {
            int b = __ffs(w) - 1; w &= w - 1;
            float4 z = z4[wi * 32 + b];
            axc += z.x; ayc += z.y; azc += z.z;
        }
    }
    for (int off = 32; off; off >>= 1) {
        axc += __shfl_down(axc, off);
        ayc += __shfl_down(ayc, off);
        azc += __shfl_down(azc, off);
    }
    if (lane == 0) {
        float dv = dinv[row];
        float lx = x2[3 * row]     - dv * axc;
        float ly = x2[3 * row + 1] - dv * ayc;
        float lz = x2[3 * row + 2] - dv * azc;
        out_curv[row] = sqrtf(lx * lx + ly * ly + lz * lz + 1e-12f);
    }
}

extern "C" void kernel_launch(void* const* d_in, const int* in_sizes, int n_in,
                              void* d_out, int out_size, void* d_ws, size_t ws_size,
                              hipStream_t stream) {
    const float* positions   = (const float*)d_in[0];
    const int*   edge_index  = (const int*)d_in[1];
    const int*   dist_idx    = (const int*)d_in[2];
    const float* dist_target = (const float*)d_in[3];
    const float* min_dist    = (const float*)d_in[4];
    float* out = (float*)d_out;

    const int E = in_sizes[1] / 2;   // 262144
    const int K = in_sizes[2] / 2;   // 65536
    const int NJ = 32;               // j-chunks in repulsion

    // workspace layout (16B aligned)
    char* ws = (char*)d_ws;
    const size_t X1_OFF   = 0;
    const size_t X2_OFF   = X1_OFF + (size_t)N_NODES * 3 * 4;          //  96 KiB
    const size_t Z4_OFF   = X2_OFF + (size_t)N_NODES * 3 * 4;          //  96 KiB
    const size_t DINV_OFF = Z4_OFF + (size_t)N_NODES * 16;             // 128 KiB
    const size_t PART_OFF = DINV_OFF + (size_t)N_NODES * 4;            //  32 KiB
    const size_t ADJ_OFF  = PART_OFF + (size_t)NJ * N_NODES * 16;      //   4 MiB
    const size_t ADJ_BYTES = (size_t)N_NODES * WPR * 4;                //   8 MiB each

    float* x1         = (float*)(ws + X1_OFF);
    float* x2         = (float*)(ws + X2_OFF);
    float4* z4        = (float4*)(ws + Z4_OFF);
    float* dinv       = (float*)(ws + DINV_OFF);
    float4* partials  = (float4*)(ws + PART_OFF);
    unsigned int* A   = (unsigned int*)(ws + ADJ_OFF);
    unsigned int* B   = (unsigned int*)(ws + ADJ_OFF + ADJ_BYTES);

    // clear A,B (16 MiB) + copy positions -> x1, one pass
    init_clear<<<4096, 256, 0, stream>>>((const float4*)positions,
                                         (float4*)x1, (uint4*)A);

    scatter_constraints<<<(K + 255) / 256, 256, 0, stream>>>(
        positions, dist_idx, dist_target, x1, K);

    build_adj<<<(E + 255) / 256, 256, 0, stream>>>(edge_index, A, B, E);

    dim3 grid_rep(N_NODES / 256, NJ);
    repulsion_partial<<<grid_rep, 256, 0, stream>>>(x1, min_dist, partials);

    int rows_per_block = 256 / 64;
    int nblk = N_NODES / rows_per_block;   // 2048
    finalize_degree<<<nblk, 256, 0, stream>>>(x1, partials, A, B,
                                              x2, out, dinv, z4);
    lap_kernel<<<nblk, 256, 0, stream>>>(A, B, x2, dinv, z4, out + 3 * N_NODES);
}